// Round 18
// baseline (213.921 us; speedup 1.0000x reference)
//
#include <hip/hip_runtime.h>
#include <math.h>

typedef float  f32x4  __attribute__((ext_vector_type(4)));
typedef int    i32x4  __attribute__((ext_vector_type(4)));

#define H      4096
#define E      64
#define TOPK   8
#define TILE_T 32
#define CK     256     // k per staged chunk
#define MS     4       // 64-k MFMA steps per chunk
#define NCH    16      // chunks

// W -> 5 balanced i8 limbs of round(w*2^41), B-fragment order for 16x16x64
// (R11-proven): Wb[((m*4+eq)*5+j)*1024 + lane*16 + slot], lane=(kgrp<<4)|(e&15)
__global__ __launch_bounds__(256)
void prep_w(const float* __restrict__ Wg, signed char* __restrict__ Wb)
{
  int n = blockIdx.x * 256 + threadIdx.x;   // 16384 = e(64) x m(64) x kgrp(4)
  int kgrp = n & 3, m = (n >> 2) & 63, e = n >> 8;
  const float* wp = Wg + e * 4096 + m * 64 + kgrp * 16;
  signed char lb[5][16];
  #pragma unroll
  for (int s = 0; s < 16; ++s) {
    long long v = (long long)rint((double)wp[s] * 2199023255552.0); // 2^41
    #pragma unroll
    for (int j = 0; j < 4; ++j) {
      signed char b = (signed char)(v & 0xff);
      lb[j][s] = b;
      v = (v - b) >> 8;
    }
    lb[4][s] = (signed char)v;
  }
  int lanei = (kgrp << 4) | (e & 15);
  int eq = e >> 4;
  #pragma unroll
  for (int j = 0; j < 5; ++j) {
    i32x4 d;
    #pragma unroll
    for (int r = 0; r < 4; ++r)
      d[r] = (lb[j][4*r] & 0xFF) | ((lb[j][4*r+1] & 0xFF) << 8)
           | ((lb[j][4*r+2] & 0xFF) << 16) | ((lb[j][4*r+3] & 0xFF) << 24);
    *(i32x4*)(Wb + (((size_t)(m * 4 + eq) * 5 + j) << 10) + lanei * 16) = d;
  }
}

// comp[e] = C0 * sum_k round(w*2^41), full K (R11-proven).
__global__ __launch_bounds__(64)
void comp_w(const float* __restrict__ Wg, double* __restrict__ compT)
{
  int e = blockIdx.x;
  int lane = threadIdx.x;
  double s = 0.0;
  #pragma unroll 4
  for (int i = 0; i < 64; ++i)
    s += rint((double)Wg[e * 4096 + i * 64 + lane] * 2199023255552.0);
  #pragma unroll
  for (int off = 32; off >= 1; off >>= 1)
    s += __shfl_xor(s, off);
  if (lane == 0) compT[e] = 8421504.0 * s;
}

// R18 = R17 producer/consumer + CONTINUOUS X stream: producers keep 8-16
// global loads outstanding at ALL times (two reg chunk-sets, issue c+2 before
// converting c+1 -> compiler emits counted vmcnt(8)), and the per-phase
// barrier is raw s_barrier + lgkmcnt(0) (NOT __syncthreads) so in-flight
// global->reg loads are not drained (T3/T4). R9-R17 all ran at dur ==
// FETCH/900GB/s: X-stream duty ~13%; this makes duty ~100%.
__global__ __launch_bounds__(512)
void moe_gate_i8(const float* __restrict__ X, const signed char* __restrict__ Wb,
                 const double* __restrict__ compT, float* __restrict__ out,
                 int n_tokens)
{
  __shared__ char sm[65536];       // 2 x 32KB limb buffers
  double* Ls = (double*)sm;        // aliased epilogue logits [32][64]

  const int tid  = threadIdx.x;
  const int lane = tid & 63;
  const int w    = tid >> 6;     // 0..7: 0-3 consumers, 4-7 producers
  const int t0   = blockIdx.x * TILE_T;
  const int l15  = lane & 15;
  const int kg   = lane >> 4;

  // ---- probe (lane,reg)->(row,col) readout (R11-proven) ----
  i32x4 z = {0, 0, 0, 0};
  int lab = l15 * 0x01010101;
  i32x4 onev = {0x01010101, 0x01010101, 0x01010101, 0x01010101};
  i32x4 labv = {lab, lab, lab, lab};
  i32x4 pr = __builtin_amdgcn_mfma_i32_16x16x64_i8(labv, onev, z, 0, 0, 0);
  i32x4 pc = __builtin_amdgcn_mfma_i32_16x16x64_i8(onev, labv, z, 0, 0, 0);
  int qrow[4], qcol[4];
  #pragma unroll
  for (int r = 0; r < 4; ++r) { qrow[r] = pr[r] >> 6; qcol[r] = pc[r] >> 6; }

  // consumer state
  i32x4 aA3 = z, aA4 = z, aA5 = z, aA6 = z, aA7 = z;
  i32x4 aB3 = z, aB4 = z, aB5 = z, aB6 = z, aB7 = z;
  const signed char* bpp = Wb + (w & 3) * 5120 + lane * 16;

  // producer state (waves 4-7); (w-4)&3 == w&3 for w in 4..7
  const int tt = (w & 3) * 8 + (lane >> 3);
  const int ks = lane & 7;
  const float* xp = X + (size_t)(t0 + tt) * H + ks * 32;
  const int swzw = ks << 4;
  char* wb0 = sm + ((ks * 2 + 0) << 11) + (((tt & 31) << 4) ^ swzw);
  char* wb1 = sm + ((ks * 2 + 1) << 11) + (((tt & 31) << 4) ^ swzw);

  f32x4 xrE[8], xrO[8];   // two chunk reg-sets (static parity, rule #20)

  #define ISSUE(c_, xr_)                                                      \
  {                                                                           \
    _Pragma("unroll")                                                         \
    for (int q = 0; q < 8; ++q)                                               \
      xr_[q] = *(const f32x4*)(xp + (size_t)(c_) * CK + 4 * q);               \
  }

  // CONV: 4 x f32x4 -> 4 limb-plane words (R9-proven perm tree)
  #define CONV(xr, hf, W0, W1, W2, W3)                                        \
  {                                                                           \
    unsigned w32[16];                                                         \
    _Pragma("unroll")                                                         \
    for (int r = 0; r < 4; ++r) {                                             \
      f32x4 xv = xr[(hf) * 4 + r];                                            \
      _Pragma("unroll")                                                       \
      for (int jj = 0; jj < 4; ++jj)                                          \
        w32[r*4+jj] = ((unsigned)(int)(xv[jj] * 268435456.0f)) ^ 0x00808080u; \
    }                                                                         \
    _Pragma("unroll")                                                         \
    for (int r = 0; r < 4; ++r) {                                             \
      unsigned u0 = w32[4*r], u1 = w32[4*r+1], u2 = w32[4*r+2], u3 = w32[4*r+3];\
      unsigned p01, p23;                                                      \
      p01 = __builtin_amdgcn_perm(u1, u0, 0x04000400u);                       \
      p23 = __builtin_amdgcn_perm(u3, u2, 0x04000400u);                       \
      W0[r] = (int)__builtin_amdgcn_perm(p23, p01, 0x05040100u);              \
      p01 = __builtin_amdgcn_perm(u1, u0, 0x05010501u);                       \
      p23 = __builtin_amdgcn_perm(u3, u2, 0x05010501u);                       \
      W1[r] = (int)__builtin_amdgcn_perm(p23, p01, 0x05040100u);              \
      p01 = __builtin_amdgcn_perm(u1, u0, 0x06020602u);                       \
      p23 = __builtin_amdgcn_perm(u3, u2, 0x06020602u);                       \
      W2[r] = (int)__builtin_amdgcn_perm(p23, p01, 0x05040100u);              \
      p01 = __builtin_amdgcn_perm(u1, u0, 0x07030703u);                       \
      p23 = __builtin_amdgcn_perm(u3, u2, 0x07030703u);                       \
      W3[r] = (int)__builtin_amdgcn_perm(p23, p01, 0x05040100u);              \
    }                                                                         \
  }

  #define PRODUCE_FROM(xr_, bufoff_)                                          \
  {                                                                           \
    i32x4 U0, U1, U2, U3, V0, V1, V2, V3;                                     \
    CONV(xr_, 0, U0, U1, U2, U3);                                             \
    CONV(xr_, 1, V0, V1, V2, V3);                                             \
    char* b0_ = wb0 + (bufoff_);                                              \
    char* b1_ = wb1 + (bufoff_);                                              \
    *(i32x4*)(b0_ + 0x000) = U0;                                              \
    *(i32x4*)(b0_ + 0x200) = U1;                                              \
    *(i32x4*)(b0_ + 0x400) = U2;                                              \
    *(i32x4*)(b0_ + 0x600) = U3;                                              \
    *(i32x4*)(b1_ + 0x000) = V0;                                              \
    *(i32x4*)(b1_ + 0x200) = V1;                                              \
    *(i32x4*)(b1_ + 0x400) = V2;                                              \
    *(i32x4*)(b1_ + 0x600) = V3;                                              \
  }

  #define CONSUME(baseoff_)                                                   \
  {                                                                           \
    const char* base_ = sm + (baseoff_);                                      \
    _Pragma("unroll")                                                         \
    for (int m = 0; m < MS; ++m) {                                            \
      const int kq   = 4 * m + kg;                                            \
      const int swzr = ((kq >> 1) & 7) << 4;                                  \
      const char* abase = base_ + (kq << 11) + (((l15 << 4) ^ swzr));         \
      i32x4 b0 = *(const i32x4*)(bpp);                                        \
      i32x4 b1 = *(const i32x4*)(bpp + 1024);                                 \
      i32x4 b2 = *(const i32x4*)(bpp + 2048);                                 \
      i32x4 b3 = *(const i32x4*)(bpp + 3072);                                 \
      i32x4 b4 = *(const i32x4*)(bpp + 4096);                                 \
      bpp += 20480;                                                           \
      i32x4 xA0 = *(const i32x4*)(abase + 0x000);                             \
      i32x4 xA1 = *(const i32x4*)(abase + 0x200);                             \
      i32x4 xA2 = *(const i32x4*)(abase + 0x400);                             \
      i32x4 xA3 = *(const i32x4*)(abase + 0x600);                             \
      i32x4 xB0 = *(const i32x4*)(abase + 0x100);                             \
      i32x4 xB1 = *(const i32x4*)(abase + 0x300);                             \
      i32x4 xB2 = *(const i32x4*)(abase + 0x500);                             \
      i32x4 xB3 = *(const i32x4*)(abase + 0x700);                             \
      aA3 = __builtin_amdgcn_mfma_i32_16x16x64_i8(xA0, b3, aA3, 0, 0, 0);     \
      aB3 = __builtin_amdgcn_mfma_i32_16x16x64_i8(xB0, b3, aB3, 0, 0, 0);     \
      aA4 = __builtin_amdgcn_mfma_i32_16x16x64_i8(xA0, b4, aA4, 0, 0, 0);     \
      aB4 = __builtin_amdgcn_mfma_i32_16x16x64_i8(xB0, b4, aB4, 0, 0, 0);     \
      aA5 = __builtin_amdgcn_mfma_i32_16x16x64_i8(xA1, b4, aA5, 0, 0, 0);     \
      aB5 = __builtin_amdgcn_mfma_i32_16x16x64_i8(xB1, b4, aB5, 0, 0, 0);     \
      aA6 = __builtin_amdgcn_mfma_i32_16x16x64_i8(xA2, b4, aA6, 0, 0, 0);     \
      aB6 = __builtin_amdgcn_mfma_i32_16x16x64_i8(xB2, b4, aB6, 0, 0, 0);     \
      aA7 = __builtin_amdgcn_mfma_i32_16x16x64_i8(xA3, b4, aA7, 0, 0, 0);     \
      aB7 = __builtin_amdgcn_mfma_i32_16x16x64_i8(xB3, b4, aB7, 0, 0, 0);     \
      aA3 = __builtin_amdgcn_mfma_i32_16x16x64_i8(xA1, b2, aA3, 0, 0, 0);     \
      aB3 = __builtin_amdgcn_mfma_i32_16x16x64_i8(xB1, b2, aB3, 0, 0, 0);     \
      aA4 = __builtin_amdgcn_mfma_i32_16x16x64_i8(xA1, b3, aA4, 0, 0, 0);     \
      aB4 = __builtin_amdgcn_mfma_i32_16x16x64_i8(xB1, b3, aB4, 0, 0, 0);     \
      aA5 = __builtin_amdgcn_mfma_i32_16x16x64_i8(xA2, b3, aA5, 0, 0, 0);     \
      aB5 = __builtin_amdgcn_mfma_i32_16x16x64_i8(xB2, b3, aB5, 0, 0, 0);     \
      aA6 = __builtin_amdgcn_mfma_i32_16x16x64_i8(xA3, b3, aA6, 0, 0, 0);     \
      aB6 = __builtin_amdgcn_mfma_i32_16x16x64_i8(xB3, b3, aB6, 0, 0, 0);     \
      aA3 = __builtin_amdgcn_mfma_i32_16x16x64_i8(xA2, b1, aA3, 0, 0, 0);     \
      aB3 = __builtin_amdgcn_mfma_i32_16x16x64_i8(xB2, b1, aB3, 0, 0, 0);     \
      aA4 = __builtin_amdgcn_mfma_i32_16x16x64_i8(xA2, b2, aA4, 0, 0, 0);     \
      aB4 = __builtin_amdgcn_mfma_i32_16x16x64_i8(xB2, b2, aB4, 0, 0, 0);     \
      aA5 = __builtin_amdgcn_mfma_i32_16x16x64_i8(xA3, b2, aA5, 0, 0, 0);     \
      aB5 = __builtin_amdgcn_mfma_i32_16x16x64_i8(xB3, b2, aB5, 0, 0, 0);     \
      aA3 = __builtin_amdgcn_mfma_i32_16x16x64_i8(xA3, b0, aA3, 0, 0, 0);     \
      aB3 = __builtin_amdgcn_mfma_i32_16x16x64_i8(xB3, b0, aB3, 0, 0, 0);     \
      aA4 = __builtin_amdgcn_mfma_i32_16x16x64_i8(xA3, b1, aA4, 0, 0, 0);     \
      aB4 = __builtin_amdgcn_mfma_i32_16x16x64_i8(xB3, b1, aB4, 0, 0, 0);     \
    }                                                                         \
  }

  // light barrier: flush LDS ops only; global->reg loads stay in flight
  #define PHASE_BARRIER                                                       \
  {                                                                           \
    asm volatile("s_waitcnt lgkmcnt(0)" ::: "memory");                        \
    __builtin_amdgcn_sched_barrier(0);                                        \
    __builtin_amdgcn_s_barrier();                                             \
    __builtin_amdgcn_sched_barrier(0);                                        \
  }

  // ---- prologue: issue ch0+ch1, convert ch0 -> buf0 (vmcnt(8) auto) ----
  if (w >= 4) {
    ISSUE(0, xrE);
    ISSUE(1, xrO);
    PRODUCE_FROM(xrE, 0);
  }
  __syncthreads();

  for (int c2 = 0; c2 < NCH / 2; ++c2) {
    // phase c = 2*c2 (even): consume buf0; producers: issue c+2 -> xrE,
    // convert c+1 (xrO) -> buf1
    if (w < 4) {
      CONSUME(0);
    } else {
      const int c = 2 * c2;
      if (c < NCH - 2) ISSUE(c + 2, xrE);
      PRODUCE_FROM(xrO, 32768);
    }
    PHASE_BARRIER;

    // phase c+1 (odd): consume buf1; producers: issue c+3 -> xrO,
    // convert c+2 (xrE) -> buf0
    if (w < 4) {
      CONSUME(32768);
    } else {
      const int c = 2 * c2 + 1;
      if (c < NCH - 2) ISSUE(c + 2, xrO);
      if (c < NCH - 1) PRODUCE_FROM(xrE, 0);
    }
    PHASE_BARRIER;
  }
  #undef ISSUE
  #undef CONV
  #undef PRODUCE_FROM
  #undef CONSUME
  #undef PHASE_BARRIER

  // ---- f64 combine (consumers own accs; staging dead -> Ls aliases sm) ----
  if (w < 4) {
    #pragma unroll
    for (int r = 0; r < 4; ++r) {
      int ex = (w & 3) * 16 + qcol[r];
      double pA = (16777216.0          * (double)aA3[r]
                 + 4294967296.0        * (double)aA4[r]
                 + 1099511627776.0     * (double)aA5[r]
                 + 281474976710656.0   * (double)aA6[r]
                 + 72057594037927936.0 * (double)aA7[r]
                 + compT[ex]) * 1.6940658945086007e-21;
      double pB = (16777216.0          * (double)aB3[r]
                 + 4294967296.0        * (double)aB4[r]
                 + 1099511627776.0     * (double)aB5[r]
                 + 281474976710656.0   * (double)aB6[r]
                 + 72057594037927936.0 * (double)aB7[r]
                 + compT[ex]) * 1.6940658945086007e-21;
      Ls[qrow[r] * E + ex]        = pA;
      Ls[(16 + qrow[r]) * E + ex] = pB;
    }
  }
  __syncthreads();

  // ---- softmax + top-8 on f64 logits: 8 waves x 4 tokens ----
  for (int tt2 = 0; tt2 < 4; tt2++) {
    int t = w * 4 + tt2;
    double val = Ls[t * E + lane];

    double mx = val;
    #pragma unroll
    for (int off = 32; off >= 1; off >>= 1)
      mx = fmax(mx, __shfl_xor(mx, off));

    float p = expf((float)(val - mx));
    float S = p;
    #pragma unroll
    for (int off = 32; off >= 1; off >>= 1)
      S += __shfl_xor(S, off);

    double cur = val;
    float myw = 0.f; int myidx = 0;
    float psum = 0.f;
    #pragma unroll
    for (int r = 0; r < TOPK; r++) {
      double v = cur; int ii = lane;
      #pragma unroll
      for (int off = 32; off >= 1; off >>= 1) {
        double ov = __shfl_xor(v, off);
        int    oi = __shfl_xor(ii, off);
        if (ov > v || (ov == v && oi < ii)) { v = ov; ii = oi; }
      }
      float pw = __shfl(p, ii);
      psum += pw;
      if (lane == r) { myw = pw; myidx = ii; }
      if (lane == ii) cur = -INFINITY;
    }
    float denom = psum + 1e-20f * S;
    if (lane < TOPK) {
      size_t gt = (size_t)(t0 + t);
      out[gt * TOPK + lane] = myw / denom;
      out[(size_t)n_tokens * TOPK + gt * TOPK + lane] = (float)myidx;
    }
  }
}

extern "C" void kernel_launch(void* const* d_in, const int* in_sizes, int n_in,
                              void* d_out, int out_size, void* d_ws, size_t ws_size,
                              hipStream_t stream)
{
  const float* X  = (const float*)d_in[0];
  const float* Wg = (const float*)d_in[1];
  float* out = (float*)d_out;
  signed char* Wb = (signed char*)d_ws;                 // 1.25 MB limb planes
  double* compT   = (double*)((char*)d_ws + 1310720);   // 512 B comp table
  int n_tokens = in_sizes[0] / H;                        // 16384

  prep_w<<<64, 256, 0, stream>>>(Wg, Wb);
  comp_w<<<64, 64, 0, stream>>>(Wg, compT);
  moe_gate_i8<<<n_tokens / TILE_T, 512, 0, stream>>>(X, Wb, compT, out, n_tokens);
}

// Round 19
// 192.879 us; speedup vs baseline: 1.1091x; 1.1091x over previous
//
#include <hip/hip_runtime.h>
#include <math.h>

typedef float  f32x4  __attribute__((ext_vector_type(4)));
typedef int    i32x4  __attribute__((ext_vector_type(4)));
typedef double f64x4  __attribute__((ext_vector_type(4)));

#define H      4096
#define E      64
#define TOPK   8
#define TILE_T 16
#define KQSZ   1024    // k per block (quarter)
#define CK     256     // k per staged chunk
#define MS     4       // 64-k MFMA steps per chunk
#define NCH    4       // chunks per block

#define WB_OFF   0
#define COMP_OFF 1310720
#define LG_OFF   2097152   // f64 logits [16384][64] = 8 MB

// W -> 5 balanced i8 limbs of round(w*2^41), B-fragment order for 16x16x64
// (R11-proven): Wb[((m*4+eq)*5+j)*1024 + lane*16 + slot], lane=(kgrp<<4)|(e&15)
__global__ __launch_bounds__(256)
void prep_w(const float* __restrict__ Wg, signed char* __restrict__ Wb)
{
  int n = blockIdx.x * 256 + threadIdx.x;   // 16384 = e(64) x m(64) x kgrp(4)
  int kgrp = n & 3, m = (n >> 2) & 63, e = n >> 8;
  const float* wp = Wg + e * 4096 + m * 64 + kgrp * 16;
  signed char lb[5][16];
  #pragma unroll
  for (int s = 0; s < 16; ++s) {
    long long v = (long long)rint((double)wp[s] * 2199023255552.0); // 2^41
    #pragma unroll
    for (int j = 0; j < 4; ++j) {
      signed char b = (signed char)(v & 0xff);
      lb[j][s] = b;
      v = (v - b) >> 8;
    }
    lb[4][s] = (signed char)v;
  }
  int lanei = (kgrp << 4) | (e & 15);
  int eq = e >> 4;
  #pragma unroll
  for (int j = 0; j < 5; ++j) {
    i32x4 d;
    #pragma unroll
    for (int r = 0; r < 4; ++r)
      d[r] = (lb[j][4*r] & 0xFF) | ((lb[j][4*r+1] & 0xFF) << 8)
           | ((lb[j][4*r+2] & 0xFF) << 16) | ((lb[j][4*r+3] & 0xFF) << 24);
    *(i32x4*)(Wb + (((size_t)(m * 4 + eq) * 5 + j) << 10) + lanei * 16) = d;
  }
}

// comp[kQ][e] = C0 * sum_{k in quarter} round(w*2^41) (R10-proven).
__global__ __launch_bounds__(64)
void comp_w(const float* __restrict__ Wg, double* __restrict__ compT)
{
  int b = blockIdx.x;            // 256 = kQ(4) x e(64)
  int kQ = b >> 6, e = b & 63;
  int lane = threadIdx.x;
  double s = 0.0;
  #pragma unroll 4
  for (int i = 0; i < 16; ++i)
    s += rint((double)Wg[e * 4096 + kQ * 1024 + i * 64 + lane] * 2199023255552.0);
  #pragma unroll
  for (int off = 32; off >= 1; off >>= 1)
    s += __shfl_xor(s, off);
  if (lane == 0) compT[kQ * 64 + e] = 8421504.0 * s;
}

// zero the f64 logits accumulator (1M doubles)
__global__ __launch_bounds__(256)
void zero_lg(double* __restrict__ lg)
{
  size_t i = ((size_t)blockIdx.x * 256 + threadIdx.x) * 4;
  f64x4 z4 = {0.0, 0.0, 0.0, 0.0};
  *(f64x4*)(lg + i) = z4;
}

// R19 partial: K split across blocks. grid = 1024 tiles x 4 quarters = 4096
// blocks -> 8 blocks/CU (LDS 16KB) = 100% wave occupancy; fetch phases of
// independent blocks interleave (R9-R18 law: dur == FETCH/900GB/s from ~13%
// load duty at 2-4 blocks/CU). Inner loop = R13's proven structure (CK=256).
// Exact i32 accs -> f64 partial + per-quarter comp -> atomicAdd to lg.
__global__ __launch_bounds__(256)
void moe_part(const float* __restrict__ X, const signed char* __restrict__ Wb,
              const double* __restrict__ compT, double* __restrict__ lg)
{
  __shared__ char As[16384];     // [kgrp16][limb4][tok16] x 16B, swizzled

  const int bid  = blockIdx.x;
  const int tile = bid >> 2;
  const int kQ   = bid & 3;
  const int t0   = tile * TILE_T;

  const int tid  = threadIdx.x;
  const int lane = tid & 63;
  const int w    = tid >> 6;     // expert quad 0..3
  const int l15  = lane & 15;
  const int kg   = lane >> 4;

  // ---- probe (lane,reg)->(row,col) readout (R11-proven) ----
  i32x4 z = {0, 0, 0, 0};
  int lab = l15 * 0x01010101;
  i32x4 onev = {0x01010101, 0x01010101, 0x01010101, 0x01010101};
  i32x4 labv = {lab, lab, lab, lab};
  i32x4 pr = __builtin_amdgcn_mfma_i32_16x16x64_i8(labv, onev, z, 0, 0, 0);
  i32x4 pc = __builtin_amdgcn_mfma_i32_16x16x64_i8(onev, labv, z, 0, 0, 0);
  int qrow[4], qcol[4];
  #pragma unroll
  for (int r = 0; r < 4; ++r) { qrow[r] = pr[r] >> 6; qcol[r] = pc[r] >> 6; }

  i32x4 acc3 = z, acc4 = z, acc5 = z, acc6 = z, acc7 = z;

  // staging: thread = (token tt 0..15, kgrp ks 0..15), 16 floats each
  const int tt = tid >> 4;
  const int ks = tid & 15;
  const float* xp = X + (size_t)(t0 + tt) * H + kQ * KQSZ + ks * 16;

  // B: global k64-step m = kQ*16 + local; base offset (kQ*64 + eq)*5120
  const signed char* bpp = Wb + (size_t)(kQ * 64 + w) * 5120 + lane * 16;

  for (int c = 0; c < NCH; ++c) {
    // ---- load + convert 16 floats -> 4 limb words, write LDS ----
    f32x4 xr[4];
    #pragma unroll
    for (int q = 0; q < 4; ++q)
      xr[q] = *(const f32x4*)(xp + c * CK + 4 * q);

    unsigned w32[16];
    #pragma unroll
    for (int r = 0; r < 4; ++r) {
      f32x4 xv = xr[r];
      #pragma unroll
      for (int jj = 0; jj < 4; ++jj)
        w32[r*4+jj] = ((unsigned)(int)(xv[jj] * 268435456.0f)) ^ 0x00808080u;
    }
    i32x4 W0, W1, W2, W3;
    #pragma unroll
    for (int r = 0; r < 4; ++r) {
      unsigned u0 = w32[4*r], u1 = w32[4*r+1], u2 = w32[4*r+2], u3 = w32[4*r+3];
      unsigned p01, p23;
      p01 = __builtin_amdgcn_perm(u1, u0, 0x04000400u);
      p23 = __builtin_amdgcn_perm(u3, u2, 0x04000400u);
      W0[r] = (int)__builtin_amdgcn_perm(p23, p01, 0x05040100u);
      p01 = __builtin_amdgcn_perm(u1, u0, 0x05010501u);
      p23 = __builtin_amdgcn_perm(u3, u2, 0x05010501u);
      W1[r] = (int)__builtin_amdgcn_perm(p23, p01, 0x05040100u);
      p01 = __builtin_amdgcn_perm(u1, u0, 0x06020602u);
      p23 = __builtin_amdgcn_perm(u3, u2, 0x06020602u);
      W2[r] = (int)__builtin_amdgcn_perm(p23, p01, 0x05040100u);
      p01 = __builtin_amdgcn_perm(u1, u0, 0x07030703u);
      p23 = __builtin_amdgcn_perm(u3, u2, 0x07030703u);
      W3[r] = (int)__builtin_amdgcn_perm(p23, p01, 0x05040100u);
    }
    // bijective swizzle on the tok nibble (R13-proven)
    {
      const int swzw = ((ks >> 1) & 7) << 4;
      char* base = As + (ks << 10) + (((tt << 4) ^ swzw));
      *(i32x4*)(base + 0x000) = W0;
      *(i32x4*)(base + 0x100) = W1;
      *(i32x4*)(base + 0x200) = W2;
      *(i32x4*)(base + 0x300) = W3;
    }
    __syncthreads();

    // ---- consume: MS steps x {4 ds_read + 5 B loads + 14 MFMAs} ----
    #pragma unroll
    for (int m = 0; m < MS; ++m) {
      const int kq   = 4 * m + kg;
      const int swzr = ((kq >> 1) & 7) << 4;
      const char* abase = As + (kq << 10) + (((l15 << 4) ^ swzr));
      i32x4 a0 = *(const i32x4*)(abase + 0x000);
      i32x4 a1 = *(const i32x4*)(abase + 0x100);
      i32x4 a2 = *(const i32x4*)(abase + 0x200);
      i32x4 a3 = *(const i32x4*)(abase + 0x300);
      i32x4 b0 = *(const i32x4*)(bpp);
      i32x4 b1 = *(const i32x4*)(bpp + 1024);
      i32x4 b2 = *(const i32x4*)(bpp + 2048);
      i32x4 b3 = *(const i32x4*)(bpp + 3072);
      i32x4 b4 = *(const i32x4*)(bpp + 4096);
      bpp += 20480;
      acc3 = __builtin_amdgcn_mfma_i32_16x16x64_i8(a0, b3, acc3, 0, 0, 0);
      acc4 = __builtin_amdgcn_mfma_i32_16x16x64_i8(a0, b4, acc4, 0, 0, 0);
      acc5 = __builtin_amdgcn_mfma_i32_16x16x64_i8(a1, b4, acc5, 0, 0, 0);
      acc6 = __builtin_amdgcn_mfma_i32_16x16x64_i8(a2, b4, acc6, 0, 0, 0);
      acc7 = __builtin_amdgcn_mfma_i32_16x16x64_i8(a3, b4, acc7, 0, 0, 0);
      acc3 = __builtin_amdgcn_mfma_i32_16x16x64_i8(a1, b2, acc3, 0, 0, 0);
      acc4 = __builtin_amdgcn_mfma_i32_16x16x64_i8(a1, b3, acc4, 0, 0, 0);
      acc5 = __builtin_amdgcn_mfma_i32_16x16x64_i8(a2, b3, acc5, 0, 0, 0);
      acc6 = __builtin_amdgcn_mfma_i32_16x16x64_i8(a3, b3, acc6, 0, 0, 0);
      acc3 = __builtin_amdgcn_mfma_i32_16x16x64_i8(a2, b1, acc3, 0, 0, 0);
      acc4 = __builtin_amdgcn_mfma_i32_16x16x64_i8(a2, b2, acc4, 0, 0, 0);
      acc5 = __builtin_amdgcn_mfma_i32_16x16x64_i8(a3, b2, acc5, 0, 0, 0);
      acc3 = __builtin_amdgcn_mfma_i32_16x16x64_i8(a3, b0, acc3, 0, 0, 0);
      acc4 = __builtin_amdgcn_mfma_i32_16x16x64_i8(a3, b1, acc4, 0, 0, 0);
    }
    __syncthreads();
  }

  // ---- f64 partial + per-quarter comp -> atomic accumulate ----
  #pragma unroll
  for (int r = 0; r < 4; ++r) {
    int ex = w * 16 + qcol[r];
    double part = (16777216.0              * (double)acc3[r]
                 + 4294967296.0            * (double)acc4[r]
                 + 1099511627776.0         * (double)acc5[r]
                 + 281474976710656.0       * (double)acc6[r]
                 + 72057594037927936.0     * (double)acc7[r]
                 + compT[kQ * 64 + ex]) * 1.6940658945086007e-21;
    unsafeAtomicAdd(&lg[(size_t)(t0 + qrow[r]) * E + ex], part);
  }
}

// finish: softmax + top-8 from the f64 logits array (R13-proven epilogue).
// 256 blocks x 4 waves x 16 tokens = 16384.
__global__ __launch_bounds__(256)
void moe_fin(const double* __restrict__ lg, float* __restrict__ out,
             int n_tokens)
{
  const int tid  = threadIdx.x;
  const int lane = tid & 63;
  const int wv   = tid >> 6;

  for (int i = 0; i < 16; ++i) {
    int t = blockIdx.x * 64 + wv * 16 + i;
    double val = lg[(size_t)t * E + lane];

    double mx = val;
    #pragma unroll
    for (int off = 32; off >= 1; off >>= 1)
      mx = fmax(mx, __shfl_xor(mx, off));

    float p = expf((float)(val - mx));
    float S = p;
    #pragma unroll
    for (int off = 32; off >= 1; off >>= 1)
      S += __shfl_xor(S, off);

    double cur = val;
    float myw = 0.f; int myidx = 0;
    float psum = 0.f;
    #pragma unroll
    for (int r = 0; r < TOPK; r++) {
      double v = cur; int ii = lane;
      #pragma unroll
      for (int off = 32; off >= 1; off >>= 1) {
        double ov = __shfl_xor(v, off);
        int    oi = __shfl_xor(ii, off);
        if (ov > v || (ov == v && oi < ii)) { v = ov; ii = oi; }
      }
      float pw = __shfl(p, ii);
      psum += pw;
      if (lane == r) { myw = pw; myidx = ii; }
      if (lane == ii) cur = -INFINITY;
    }
    float denom = psum + 1e-20f * S;
    if (lane < TOPK) {
      size_t gt = (size_t)t;
      out[gt * TOPK + lane] = myw / denom;
      out[(size_t)n_tokens * TOPK + gt * TOPK + lane] = (float)myidx;
    }
  }
}

extern "C" void kernel_launch(void* const* d_in, const int* in_sizes, int n_in,
                              void* d_out, int out_size, void* d_ws, size_t ws_size,
                              hipStream_t stream)
{
  const float* X  = (const float*)d_in[0];
  const float* Wg = (const float*)d_in[1];
  float* out = (float*)d_out;
  signed char* Wb = (signed char*)((char*)d_ws + WB_OFF);   // 1.25 MB
  double* compT   = (double*)((char*)d_ws + COMP_OFF);      // 2 KB
  double* lg      = (double*)((char*)d_ws + LG_OFF);        // 8 MB
  int n_tokens = in_sizes[0] / H;                            // 16384

  prep_w<<<64, 256, 0, stream>>>(Wg, Wb);
  comp_w<<<256, 64, 0, stream>>>(Wg, compT);
  zero_lg<<<1024, 256, 0, stream>>>(lg);
  moe_part<<<(n_tokens / TILE_T) * 4, 256, 0, stream>>>(X, Wb, compT, lg);
  moe_fin<<<n_tokens / 64, 256, 0, stream>>>(lg, out, n_tokens);
}

// Round 20
// 118.809 us; speedup vs baseline: 1.8005x; 1.6234x over previous
//
#include <hip/hip_runtime.h>
#include <math.h>

typedef float  f32x4  __attribute__((ext_vector_type(4)));
typedef int    i32x4  __attribute__((ext_vector_type(4)));

#define H      4096
#define E      64
#define TOPK   8
#define TILE_T 16
#define CK     256     // k per staged chunk
#define MS     4       // 64-k MFMA steps per chunk
#define NCH    16      // chunks

// W -> 5 balanced i8 limbs of round(w*2^41), B-fragment order for 16x16x64
// (R11-proven): Wb[((m*4+eq)*5+j)*1024 + lane*16 + slot], lane=(kgrp<<4)|(e&15)
__global__ __launch_bounds__(256)
void prep_w(const float* __restrict__ Wg, signed char* __restrict__ Wb)
{
  int n = blockIdx.x * 256 + threadIdx.x;   // 16384 = e(64) x m(64) x kgrp(4)
  int kgrp = n & 3, m = (n >> 2) & 63, e = n >> 8;
  const float* wp = Wg + e * 4096 + m * 64 + kgrp * 16;
  signed char lb[5][16];
  #pragma unroll
  for (int s = 0; s < 16; ++s) {
    long long v = (long long)rint((double)wp[s] * 2199023255552.0); // 2^41
    #pragma unroll
    for (int j = 0; j < 4; ++j) {
      signed char b = (signed char)(v & 0xff);
      lb[j][s] = b;
      v = (v - b) >> 8;
    }
    lb[4][s] = (signed char)v;
  }
  int lanei = (kgrp << 4) | (e & 15);
  int eq = e >> 4;
  #pragma unroll
  for (int j = 0; j < 5; ++j) {
    i32x4 d;
    #pragma unroll
    for (int r = 0; r < 4; ++r)
      d[r] = (lb[j][4*r] & 0xFF) | ((lb[j][4*r+1] & 0xFF) << 8)
           | ((lb[j][4*r+2] & 0xFF) << 16) | ((lb[j][4*r+3] & 0xFF) << 24);
    *(i32x4*)(Wb + (((size_t)(m * 4 + eq) * 5 + j) << 10) + lanei * 16) = d;
  }
}

// comp[e] = C0 * sum_k round(w*2^41), full K (R11-proven).
__global__ __launch_bounds__(64)
void comp_w(const float* __restrict__ Wg, double* __restrict__ compT)
{
  int e = blockIdx.x;
  int lane = threadIdx.x;
  double s = 0.0;
  #pragma unroll 4
  for (int i = 0; i < 64; ++i)
    s += rint((double)Wg[e * 4096 + i * 64 + lane] * 2199023255552.0);
  #pragma unroll
  for (int off = 32; off >= 1; off >>= 1)
    s += __shfl_xor(s, off);
  if (lane == 0) compT[e] = 8421504.0 * s;
}

// R20 = R13 with COALESCED staging. Old staging: each wave-load touched 64
// cache lines (16B sliver per line) -> 64 TA transactions/instr; TA-rate
// bound at ~900 GB/s (the R9-R18 law). New: wave w stages rows w*4..w*4+3,
// ONE fully-coalesced instr per row (lane*16B), per-lane CONV of its own
// f32x4 (once per block), ds_write_b32 scatter with bank = 2 lanes/bank
// (free). TILE_T=16 -> 1024 blocks -> 4 blocks/CU for cross-block desync.
// Numerics byte-identical to R8-R19.
__global__ __launch_bounds__(256)
void moe_gate_i8(const float* __restrict__ X, const signed char* __restrict__ Wb,
                 const double* __restrict__ compT, float* __restrict__ out,
                 int n_tokens)
{
  __shared__ char As[16384];     // [kgrp16][limb4][tok16]x16B, swizzled
  double* Ls = (double*)As;      // aliased epilogue logits [16][64]

  const int tid  = threadIdx.x;
  const int lane = tid & 63;
  const int w    = tid >> 6;     // expert quad 0..3 (also stager of 4 rows)
  const int t0   = blockIdx.x * TILE_T;
  const int l15  = lane & 15;
  const int kg   = lane >> 4;

  // ---- probe (lane,reg)->(row,col) readout (R11-proven) ----
  i32x4 z = {0, 0, 0, 0};
  int lab = l15 * 0x01010101;
  i32x4 onev = {0x01010101, 0x01010101, 0x01010101, 0x01010101};
  i32x4 labv = {lab, lab, lab, lab};
  i32x4 pr = __builtin_amdgcn_mfma_i32_16x16x64_i8(labv, onev, z, 0, 0, 0);
  i32x4 pc = __builtin_amdgcn_mfma_i32_16x16x64_i8(onev, labv, z, 0, 0, 0);
  int qrow[4], qcol[4];
  #pragma unroll
  for (int r = 0; r < 4; ++r) { qrow[r] = pr[r] >> 6; qcol[r] = pc[r] >> 6; }

  i32x4 acc3 = z, acc4 = z, acc5 = z, acc6 = z, acc7 = z;

  // staging: wave w stages rows w*4..w*4+3; lane covers k = lane*4..lane*4+3
  // of the chunk (fully coalesced: 64 lanes x 16B = 1KB = one row-chunk)
  const int kgrp = lane >> 2;                  // 0..15
  const int wrd  = lane & 3;                   // word within 16B group
  const int swzs = ((lane >> 3) & 7) << 4;     // ((kgrp>>1)&7)<<4
  const float* xbase = X + (size_t)t0 * H + lane * 4;

  const signed char* bpp = Wb + w * 5120 + lane * 16;

  for (int c = 0; c < NCH; ++c) {
    // ---- coalesced load: one f32x4 per row (4 rows per wave) ----
    f32x4 xr[4];
    #pragma unroll
    for (int q = 0; q < 4; ++q)
      xr[q] = *(const f32x4*)(xbase + (size_t)(w * 4 + q) * H + c * CK);

    // ---- per-lane CONV (once per block) + swizzled b32 scatter ----
    #pragma unroll
    for (int q = 0; q < 4; ++q) {
      const int r = w * 4 + q;
      unsigned u0 = ((unsigned)(int)(xr[q][0] * 268435456.0f)) ^ 0x00808080u;
      unsigned u1 = ((unsigned)(int)(xr[q][1] * 268435456.0f)) ^ 0x00808080u;
      unsigned u2 = ((unsigned)(int)(xr[q][2] * 268435456.0f)) ^ 0x00808080u;
      unsigned u3 = ((unsigned)(int)(xr[q][3] * 268435456.0f)) ^ 0x00808080u;
      unsigned p01, p23, W0, W1, W2, W3;
      p01 = __builtin_amdgcn_perm(u1, u0, 0x04000400u);
      p23 = __builtin_amdgcn_perm(u3, u2, 0x04000400u);
      W0  = __builtin_amdgcn_perm(p23, p01, 0x05040100u);
      p01 = __builtin_amdgcn_perm(u1, u0, 0x05010501u);
      p23 = __builtin_amdgcn_perm(u3, u2, 0x05010501u);
      W1  = __builtin_amdgcn_perm(p23, p01, 0x05040100u);
      p01 = __builtin_amdgcn_perm(u1, u0, 0x06020602u);
      p23 = __builtin_amdgcn_perm(u3, u2, 0x06020602u);
      W2  = __builtin_amdgcn_perm(p23, p01, 0x05040100u);
      p01 = __builtin_amdgcn_perm(u1, u0, 0x07030703u);
      p23 = __builtin_amdgcn_perm(u3, u2, 0x07030703u);
      W3  = __builtin_amdgcn_perm(p23, p01, 0x05040100u);
      // addr = kgrp<<10 | j<<8 | ((r<<4)^swzs) | wrd<<2 ; bank 2-way = free
      char* base = As + (kgrp << 10) + (((r << 4) ^ swzs)) + (wrd << 2);
      *(unsigned*)(base + 0x000) = W0;
      *(unsigned*)(base + 0x100) = W1;
      *(unsigned*)(base + 0x200) = W2;
      *(unsigned*)(base + 0x300) = W3;
    }
    __syncthreads();

    // ---- consume: MS steps x {4 ds_read + 5 B loads + 14 MFMAs} (R13) ----
    #pragma unroll
    for (int m = 0; m < MS; ++m) {
      const int kq   = 4 * m + kg;
      const int swzr = ((kq >> 1) & 7) << 4;
      const char* abase = As + (kq << 10) + (((l15 << 4) ^ swzr));
      i32x4 a0 = *(const i32x4*)(abase + 0x000);
      i32x4 a1 = *(const i32x4*)(abase + 0x100);
      i32x4 a2 = *(const i32x4*)(abase + 0x200);
      i32x4 a3 = *(const i32x4*)(abase + 0x300);
      i32x4 b0 = *(const i32x4*)(bpp);
      i32x4 b1 = *(const i32x4*)(bpp + 1024);
      i32x4 b2 = *(const i32x4*)(bpp + 2048);
      i32x4 b3 = *(const i32x4*)(bpp + 3072);
      i32x4 b4 = *(const i32x4*)(bpp + 4096);
      bpp += 20480;
      acc3 = __builtin_amdgcn_mfma_i32_16x16x64_i8(a0, b3, acc3, 0, 0, 0);
      acc4 = __builtin_amdgcn_mfma_i32_16x16x64_i8(a0, b4, acc4, 0, 0, 0);
      acc5 = __builtin_amdgcn_mfma_i32_16x16x64_i8(a1, b4, acc5, 0, 0, 0);
      acc6 = __builtin_amdgcn_mfma_i32_16x16x64_i8(a2, b4, acc6, 0, 0, 0);
      acc7 = __builtin_amdgcn_mfma_i32_16x16x64_i8(a3, b4, acc7, 0, 0, 0);
      acc3 = __builtin_amdgcn_mfma_i32_16x16x64_i8(a1, b2, acc3, 0, 0, 0);
      acc4 = __builtin_amdgcn_mfma_i32_16x16x64_i8(a1, b3, acc4, 0, 0, 0);
      acc5 = __builtin_amdgcn_mfma_i32_16x16x64_i8(a2, b3, acc5, 0, 0, 0);
      acc6 = __builtin_amdgcn_mfma_i32_16x16x64_i8(a3, b3, acc6, 0, 0, 0);
      acc3 = __builtin_amdgcn_mfma_i32_16x16x64_i8(a2, b1, acc3, 0, 0, 0);
      acc4 = __builtin_amdgcn_mfma_i32_16x16x64_i8(a2, b2, acc4, 0, 0, 0);
      acc5 = __builtin_amdgcn_mfma_i32_16x16x64_i8(a3, b2, acc5, 0, 0, 0);
      acc3 = __builtin_amdgcn_mfma_i32_16x16x64_i8(a3, b0, acc3, 0, 0, 0);
      acc4 = __builtin_amdgcn_mfma_i32_16x16x64_i8(a3, b1, acc4, 0, 0, 0);
    }
    __syncthreads();
  }

  // ---- f64 combine: wave owns its 16x16 logits (R11-proven) ----
  #pragma unroll
  for (int r = 0; r < 4; ++r) {
    int ex = w * 16 + qcol[r];
    double part = (16777216.0              * (double)acc3[r]
                 + 4294967296.0            * (double)acc4[r]
                 + 1099511627776.0         * (double)acc5[r]
                 + 281474976710656.0       * (double)acc6[r]
                 + 72057594037927936.0     * (double)acc7[r]
                 + compT[ex]) * 1.6940658945086007e-21;
    Ls[qrow[r] * E + ex] = part;
  }
  __syncthreads();

  // ---- softmax + top-8: selection on f64 logits, weights in f32 ----
  for (int tt2 = 0; tt2 < 4; tt2++) {
    int t = w * 4 + tt2;
    double val = Ls[t * E + lane];

    double mx = val;
    #pragma unroll
    for (int off = 32; off >= 1; off >>= 1)
      mx = fmax(mx, __shfl_xor(mx, off));

    float p = expf((float)(val - mx));
    float S = p;
    #pragma unroll
    for (int off = 32; off >= 1; off >>= 1)
      S += __shfl_xor(S, off);

    double cur = val;
    float myw = 0.f; int myidx = 0;
    float psum = 0.f;
    #pragma unroll
    for (int r = 0; r < TOPK; r++) {
      double v = cur; int ii = lane;
      #pragma unroll
      for (int off = 32; off >= 1; off >>= 1) {
        double ov = __shfl_xor(v, off);
        int    oi = __shfl_xor(ii, off);
        if (ov > v || (ov == v && oi < ii)) { v = ov; ii = oi; }
      }
      float pw = __shfl(p, ii);
      psum += pw;
      if (lane == r) { myw = pw; myidx = ii; }
      if (lane == ii) cur = -INFINITY;
    }
    float denom = psum + 1e-20f * S;
    if (lane < TOPK) {
      size_t gt = (size_t)(t0 + t);
      out[gt * TOPK + lane] = myw / denom;
      out[(size_t)n_tokens * TOPK + gt * TOPK + lane] = (float)myidx;
    }
  }
}

extern "C" void kernel_launch(void* const* d_in, const int* in_sizes, int n_in,
                              void* d_out, int out_size, void* d_ws, size_t ws_size,
                              hipStream_t stream)
{
  const float* X  = (const float*)d_in[0];
  const float* Wg = (const float*)d_in[1];
  float* out = (float*)d_out;
  signed char* Wb = (signed char*)d_ws;                 // 1.25 MB limb planes
  double* compT   = (double*)((char*)d_ws + 1310720);   // 512 B comp table
  int n_tokens = in_sizes[0] / H;                        // 16384

  prep_w<<<64, 256, 0, stream>>>(Wg, Wb);
  comp_w<<<64, 64, 0, stream>>>(Wg, compT);
  moe_gate_i8<<<n_tokens / TILE_T, 256, 0, stream>>>(X, Wb, compT, out, n_tokens);
}